// Round 9
// baseline (505.539 us; speedup 1.0000x reference)
//
#include <hip/hip_runtime.h>

// expRNN/modReLU recurrence, B=8192, T=784, I=1, H=30, C=10.
//
// Round 9: TWO independent 16-batch streams per wave (32 batches/wave,
// 256 blocks x 1 wave). No barriers, no exchange — each stream uses the
// verified R6 layout identity (A-frag rows interleaved 8*(m>>2)+(m&3)+4g
// => MFMA C-layout == next step's B-layout, lane (m,q) owns h rows
// 8q..8q+7 of its batch).
//
// Rationale (R6/R7/R8 model): MFMA 16x16x32 occupies the matrix pipe
// ~19 cyc, epilogue ~200 VALU cyc; in a single-stream wave the two pipes
// run serially (679 cyc/iter measured) and half the SIMDs idle. Stream
// S0's epilogue VALU overlaps S1's MFMA-port time and vice versa:
// wall ~ max(24*19, 2*200) ~ 500 cyc for 32 batches -> ~165 us.
// Body order [S0 mfma][S1 mfma][S0 epi][S1 epi] keeps each stream's
// producer->consumer distance one full phase apart.
//
// Numerics bit-identical to R6/R7 (same 6 split-term products, same
// per-chain order, x as f32 acc-init): expect absmax == 3.169127e+29.

#define T_STEPS 784
#define NBATCH  8192
#define NH      30
#define NC      10
#define NS      2     // streams per wave
#define BPW     32    // batches per wave (NS * 16)
#define XPAD    788   // padded x row; bank spread (20*b mod 32) -> 2-way max

typedef short bf16x8 __attribute__((ext_vector_type(8)));
typedef float f32x4  __attribute__((ext_vector_type(4)));
typedef unsigned int u32x4 __attribute__((ext_vector_type(4)));

#define MFMA(acc, a, b) \
    acc = __builtin_amdgcn_mfma_f32_16x16x32_bf16(a, b, acc, 0, 0, 0)

static __device__ __forceinline__ float truncbf(float x) {
    return __int_as_float(__float_as_int(x) & 0xFFFF0000);
}
// dword = bf16(lo) | bf16(hi)<<16 (hi16 bit-slices via byte perm)
static __device__ __forceinline__ unsigned pk2(float lo, float hi) {
    return __builtin_amdgcn_perm(__float_as_uint(hi), __float_as_uint(lo),
                                 0x07060302u);
}
static __device__ __forceinline__ bf16x8 pk8(const float* v) {
    u32x4 u = { pk2(v[0], v[1]), pk2(v[2], v[3]),
                pk2(v[4], v[5]), pk2(v[6], v[7]) };
    return __builtin_bit_cast(bf16x8, u);
}
static __device__ __forceinline__ float modrelu(float z, float b) {
    return copysignf(fmaxf(fabsf(z) + b, 0.0f), z);
}

__global__ __launch_bounds__(64, 1)
void rnn_2stream(const float* __restrict__ inp,    // [B, T, 1]
                 const float* __restrict__ W_ih,   // [H, 1]
                 const float* __restrict__ W_hh,   // [H, H]
                 const float* __restrict__ b_mod,  // [H]
                 const float* __restrict__ W_lin,  // [C, H]
                 const float* __restrict__ b_lin,  // [C]
                 float* __restrict__ out)          // [B, C]
{
    __shared__ __align__(16) float xl[BPW * XPAD];   // 100.9 KB
    __shared__ __align__(16) float hf[BPW * 36];     // 4.6 KB

    const int l   = threadIdx.x;
    const int blk = blockIdx.x;
    const int m   = l & 15;     // batch column within a stream
    const int q   = l >> 4;     // quad: owns h rows 8q..8q+7

    // ---- stage x: 32 batches x 784 floats = 6272 float4, coalesced ----
    {
        const float4* src = (const float4*)(inp + (size_t)blk * (BPW * T_STEPS));
        #pragma unroll
        for (int k = 0; k < 98; ++k) {
            int v = l + 64 * k;                 // exactly covers 6272
            int b   = v / 196;                  // 196 float4 per batch row
            int rem = v - b * 196;
            *(float4*)(xl + b * XPAD + 4 * rem) = src[v];
        }
    }

    // ---- A fragments (shared by both streams): 2 row-groups x 3 terms ----
    bf16x8 afr[2][3];
    #pragma unroll
    for (int g = 0; g < 2; ++g) {
        const int row = 8 * (m >> 2) + (m & 3) + 4 * g;   // W row at A-pos m
        float wv[8], r1v[8], r2v[8];
        #pragma unroll
        for (int j = 0; j < 8; ++j) {
            const int col = q * 8 + j;
            float v = (row < NH && col < NH) ? W_hh[row * NH + col] : 0.0f;
            wv[j]  = v;
            r1v[j] = v - truncbf(v);
            r2v[j] = r1v[j] - truncbf(r1v[j]);
        }
        afr[g][0] = pk8(wv);
        afr[g][1] = pk8(r1v);
        afr[g][2] = pk8(r2v);
    }

    // per-lane row metadata: lane owns h rows 8q+i
    float bm[8], wih[8];
    #pragma unroll
    for (int i = 0; i < 8; ++i) {
        const int row = 8 * q + i;
        bm[i]  = (row < NH) ? b_mod[row] : 0.0f;
        wih[i] = (row < NH) ? W_ih[row]  : 0.0f;
    }

    __syncthreads();

    // per-stream state
    const float* xb[NS];
    float xcur[NS], xnx[NS];
    bf16x8 bf1[NS], bf2[NS], bf3[NS];
    float hv[NS][8];
    #pragma unroll
    for (int s = 0; s < NS; ++s) {
        xb[s]   = xl + (16 * s + m) * XPAD;
        xcur[s] = xb[s][0];
        xnx[s]  = xb[s][1];
        bf1[s] = (bf16x8){};
        bf2[s] = (bf16x8){};
        bf3[s] = (bf16x8){};
        #pragma unroll
        for (int i = 0; i < 8; ++i) hv[s][i] = 0.0f;
    }

    // ---- recurrence ----
    #pragma unroll 1
    for (int t = 0; t < T_STEPS; ++t) {
        int tf = t + 2; if (tf >= T_STEPS) tf = T_STEPS - 1;
        float xf[NS];
        f32x4 c0a[NS], c0b[NS], c1a[NS], c1b[NS];

        // phase 1: both streams' MFMA groups back-to-back on the matrix
        // pipe; stream s's epilogue later overlaps the other's MFMAs.
        #pragma unroll
        for (int s = 0; s < NS; ++s) {
            xf[s] = xb[s][tf];                 // prefetch x_{t+2}
            #pragma unroll
            for (int i = 0; i < 4; ++i) {
                c0a[s][i] = wih[i]     * xcur[s];
                c1a[s][i] = wih[4 + i] * xcur[s];
            }
            c0b[s] = (f32x4){0.f, 0.f, 0.f, 0.f};
            c1b[s] = (f32x4){0.f, 0.f, 0.f, 0.f};

            // 4 independent 3-deep chains (R6's best ordering)
            MFMA(c0a[s], afr[0][0], bf1[s]);   // w1h1
            MFMA(c1a[s], afr[1][0], bf1[s]);
            MFMA(c0b[s], afr[0][1], bf1[s]);   // w2h1
            MFMA(c1b[s], afr[1][1], bf1[s]);
            MFMA(c0a[s], afr[0][0], bf2[s]);   // w1h2
            MFMA(c1a[s], afr[1][0], bf2[s]);
            MFMA(c0b[s], afr[0][1], bf2[s]);   // w2h2
            MFMA(c1b[s], afr[1][1], bf2[s]);
            MFMA(c0a[s], afr[0][0], bf3[s]);   // w1h3
            MFMA(c1a[s], afr[1][0], bf3[s]);
            MFMA(c0b[s], afr[0][2], bf1[s]);   // w3h1
            MFMA(c1b[s], afr[1][2], bf1[s]);
        }

        // phase 2: epilogues (VALU) — overlap the other stream's MFMAs
        #pragma unroll
        for (int s = 0; s < NS; ++s) {
            #pragma unroll
            for (int i = 0; i < 4; ++i) {
                const float z0 = c0a[s][i] + c0b[s][i];
                const float z1 = c1a[s][i] + c1b[s][i];
                hv[s][i]     = modrelu(z0, bm[i]);
                hv[s][4 + i] = modrelu(z1, bm[4 + i]);
            }
            float r1[8], r2[8];
            #pragma unroll
            for (int j = 0; j < 8; ++j) {
                r1[j] = hv[s][j] - truncbf(hv[s][j]);
                r2[j] = r1[j] - truncbf(r1[j]);
            }
            bf1[s] = pk8(hv[s]);
            bf2[s] = pk8(r1);
            bf3[s] = pk8(r2);
            xcur[s] = xnx[s];
            xnx[s]  = xf[s];
        }
    }

    // ---- stash h for the classifier ----
    #pragma unroll
    for (int s = 0; s < NS; ++s) {
        *(float4*)(hf + (16 * s + m) * 36 + 8 * q) =
            make_float4(hv[s][0], hv[s][1], hv[s][2], hv[s][3]);
        *(float4*)(hf + (16 * s + m) * 36 + 8 * q + 4) =
            make_float4(hv[s][4], hv[s][5], hv[s][6], hv[s][7]);
    }
    __syncthreads();

    // ---- classifier: 320 outputs (32 batches x 10 classes) ----
    #pragma unroll
    for (int it = 0; it < 5; ++it) {
        const int k = l + 64 * it;              // exactly covers 320
        const int b = k / NC;
        const int c = k % NC;
        float acc = b_lin[c];
        #pragma unroll
        for (int i = 0; i < NH; ++i) {
            acc = fmaf(W_lin[c * NH + i], hf[b * 36 + i], acc);
        }
        out[((size_t)blk * BPW + b) * NC + c] = acc;
    }
}

extern "C" void kernel_launch(void* const* d_in, const int* in_sizes, int n_in,
                              void* d_out, int out_size, void* d_ws, size_t ws_size,
                              hipStream_t stream) {
    const float* inp   = (const float*)d_in[0];
    const float* W_ih  = (const float*)d_in[1];
    const float* W_hh  = (const float*)d_in[2];
    const float* b_mod = (const float*)d_in[3];
    const float* W_lin = (const float*)d_in[4];
    const float* b_lin = (const float*)d_in[5];
    float* out = (float*)d_out;

    dim3 grid(NBATCH / BPW);   // 256 blocks
    dim3 block(64);            // one wave, two streams
    rnn_2stream<<<grid, block, 0, stream>>>(inp, W_ih, W_hh, b_mod,
                                            W_lin, b_lin, out);
}

// Round 10
// 267.722 us; speedup vs baseline: 1.8883x; 1.8883x over previous
//
#include <hip/hip_runtime.h>

// expRNN/modReLU recurrence, B=8192, T=784, I=1, H=30, C=10.
//
// Round 10: R8 row-split with a minimized exchange critical path.
// Machine model (fit R6/R7/R8/R9 exactly): one v_mfma_16x16x32 BLOCKS its
// wave ~40 cyc (in-order, no within-wave overlap, R9 falsified it at
// 24x41+400=1387); per-iter wall = #MFMA*40 + VALU + exchange. R8's
// exchange measured ~310 vs ~210 floor. Changes vs R8 (numerics
// bit-identical -> absmax must be exactly 3.169127e+29):
//   1. Publish each packed term AS SOON as computed (bf1 right after
//      modrelu; then bf2; then bf3) -> the pre-barrier lgkmcnt(0) drain
//      starts ~40 cyc earlier (R8 computed all splits, then all writes).
//   2. Post-barrier: frag reads issued first (bf1,bf2,bf3), then the x
//      prefetch, then ca/cb init VALU in the read shadow; MFMA1 waits only
//      bf1 (fine-grained lgkm); bf2/bf3 return under MFMA1-3 block time.
//   3. Same ex layout (2-way banks = free), same 6 MFMAs as two 3-deep
//      chains, same classifier.
// Decision rule: if this lands >=~208 us, the ~640 cyc/iter convergence of
// three architectures is the sequential-latency floor -> roofline.

#define T_STEPS 784
#define NBATCH  8192
#define NH      30
#define NC      10
#define BPW     16    // batches per block (= MFMA N)
#define XPAD    788   // padded x row; bank spread 20m mod 32 -> 2-way max

typedef short bf16x8 __attribute__((ext_vector_type(8)));
typedef float f32x4  __attribute__((ext_vector_type(4)));
typedef unsigned int u32x4 __attribute__((ext_vector_type(4)));
typedef unsigned int u32x2 __attribute__((ext_vector_type(2)));

#define MFMA(acc, a, b) \
    acc = __builtin_amdgcn_mfma_f32_16x16x32_bf16(a, b, acc, 0, 0, 0)

static __device__ __forceinline__ float truncbf(float x) {
    return __int_as_float(__float_as_int(x) & 0xFFFF0000);
}
// dword = bf16(lo) | bf16(hi)<<16 (hi16 bit-slices via byte perm)
static __device__ __forceinline__ unsigned pk2(float lo, float hi) {
    return __builtin_amdgcn_perm(__float_as_uint(hi), __float_as_uint(lo),
                                 0x07060302u);
}
static __device__ __forceinline__ bf16x8 pk8(const float* v) {
    u32x4 u = { pk2(v[0], v[1]), pk2(v[2], v[3]),
                pk2(v[4], v[5]), pk2(v[6], v[7]) };
    return __builtin_bit_cast(bf16x8, u);
}
static __device__ __forceinline__ float modrelu(float z, float b) {
    return copysignf(fmaxf(fabsf(z) + b, 0.0f), z);
}

__global__ __launch_bounds__(128, 1)
void rnn_rowsplit2(const float* __restrict__ inp,    // [B, T, 1]
                   const float* __restrict__ W_ih,   // [H, 1]
                   const float* __restrict__ W_hh,   // [H, H]
                   const float* __restrict__ b_mod,  // [H]
                   const float* __restrict__ W_lin,  // [C, H]
                   const float* __restrict__ b_lin,  // [C]
                   float* __restrict__ out)          // [B, C]
{
    __shared__ __align__(16) float xl[BPW * XPAD];            // 50.4 KB
    __shared__ __align__(16) unsigned ex[2][3][4][16][4];     // 6 KB
    __shared__ __align__(16) float hf[BPW * 36];              // 2.3 KB

    const int tid = threadIdx.x;
    const int g   = tid >> 6;    // wave id: row-group
    const int l   = tid & 63;
    const int m   = l & 15;      // batch column
    const int q   = l >> 4;      // quad: B-frag k-range 8q..8q+7
    const int blk = blockIdx.x;

    // ---- stage x: 16 batches x 784 floats, coalesced, padded rows ----
    {
        const float4* src = (const float4*)(inp + (size_t)blk * (BPW * T_STEPS));
        #pragma unroll
        for (int k = 0; k < 25; ++k) {
            int v = tid + 128 * k;              // < 3136 float4
            if (v < (BPW * T_STEPS) / 4) {
                int b   = v / 196;
                int rem = v - b * 196;
                *(float4*)(xl + b * XPAD + 4 * rem) = src[v];
            }
        }
    }

    // ---- A fragments (this wave's row-group), 3 exact split terms ----
    bf16x8 a1, a2, a3;
    {
        const int row = 8 * (m >> 2) + (m & 3) + 4 * g;  // W row at A-pos m
        float wv[8], r1v[8], r2v[8];
        #pragma unroll
        for (int j = 0; j < 8; ++j) {
            const int col = q * 8 + j;
            float v = (row < NH && col < NH) ? W_hh[row * NH + col] : 0.0f;
            wv[j]  = v;
            r1v[j] = v - truncbf(v);
            r2v[j] = r1v[j] - truncbf(r1v[j]);
        }
        a1 = pk8(wv); a2 = pk8(r1v); a3 = pk8(r2v);
    }

    // own C rows: 8q + 4g + i
    float bm[4], wih[4];
    #pragma unroll
    for (int i = 0; i < 4; ++i) {
        const int row = 8 * q + 4 * g + i;
        bm[i]  = (row < NH) ? b_mod[row] : 0.0f;
        wih[i] = (row < NH) ? W_ih[row]  : 0.0f;
    }

    __syncthreads();

    const float* xb = xl + m * XPAD;
    float xcur = xb[0];
    float xnx  = xb[1];

    bf16x8 bf1 = {}, bf2 = {}, bf3 = {};     // h_0 = 0
    float hv[4] = {0.0f, 0.0f, 0.0f, 0.0f};

    // exchange slots (dword units); term stride = 256 dwords
    unsigned* const wr0 = &ex[0][0][q][m][2 * g];
    unsigned* const wr1 = &ex[1][0][q][m][2 * g];
    const unsigned* const rd0 = &ex[0][0][q][m][0];
    const unsigned* const rd1 = &ex[1][0][q][m][0];

    #pragma unroll 2
    for (int t = 0; t < T_STEPS; ++t) {
        // two independent 3-deep MFMA chains; ca carries the f32 x-term.
        // bf1-consumers first: bf2/bf3 reads may still be in flight and
        // their waits land under MFMA1-3's block time.
        f32x4 ca, cb;
        #pragma unroll
        for (int i = 0; i < 4; ++i) ca[i] = wih[i] * xcur;
        cb = (f32x4){0.0f, 0.0f, 0.0f, 0.0f};

        MFMA(ca, a1, bf1);   MFMA(cb, a2, bf1);   // w1h1 | w2h1
        MFMA(ca, a3, bf1);   MFMA(cb, a1, bf2);   // w3h1 | w1h2
        MFMA(ca, a2, bf2);   MFMA(cb, a1, bf3);   // w2h2 | w1h3

        // modReLU on own 4 rows (pad rows: w,b,wih==0 -> stay 0)
        #pragma unroll
        for (int i = 0; i < 4; ++i) hv[i] = modrelu(ca[i] + cb[i], bm[i]);

        unsigned* w = (t & 1) ? wr1 : wr0;

        // --- publish term 1 IMMEDIATELY (shortens pre-barrier drain) ---
        *(u32x2*)(w + 0) = (u32x2){ pk2(hv[0], hv[1]), pk2(hv[2], hv[3]) };

        // exact residual 1 -> publish term 2
        float r1[4];
        #pragma unroll
        for (int i = 0; i < 4; ++i) r1[i] = hv[i] - truncbf(hv[i]);
        *(u32x2*)(w + 256) = (u32x2){ pk2(r1[0], r1[1]), pk2(r1[2], r1[3]) };

        // exact residual 2 -> publish term 3
        float r2[4];
        #pragma unroll
        for (int i = 0; i < 4; ++i) r2[i] = r1[i] - truncbf(r1[i]);
        *(u32x2*)(w + 512) = (u32x2){ pk2(r2[0], r2[1]), pk2(r2[2], r2[3]) };

        __syncthreads();   // drain + publish; double-buffer -> 1 barrier

        // frag reads first (bf1 oldest -> MFMA1 waits only on it), then x
        const unsigned* r = (t & 1) ? rd1 : rd0;
        bf1 = __builtin_bit_cast(bf16x8, *(const u32x4*)(r + 0));
        bf2 = __builtin_bit_cast(bf16x8, *(const u32x4*)(r + 256));
        bf3 = __builtin_bit_cast(bf16x8, *(const u32x4*)(r + 512));

        int tf = t + 2; if (tf >= T_STEPS) tf = T_STEPS - 1;
        const float xf = xb[tf];             // prefetch x_{t+2}
        xcur = xnx; xnx = xf;
    }

    // ---- stash own f32 rows of h_T for the classifier ----
    *(float4*)(hf + m * 36 + 8 * q + 4 * g) =
        make_float4(hv[0], hv[1], hv[2], hv[3]);
    __syncthreads();

    // ---- classifier: 160 outputs (16 batches x 10 classes) ----
    #pragma unroll
    for (int it = 0; it < 2; ++it) {
        const int k = tid + 128 * it;
        if (k < BPW * NC) {
            const int b = k / NC;
            const int c = k % NC;
            float acc = b_lin[c];
            #pragma unroll
            for (int i = 0; i < NH; ++i) {
                acc = fmaf(W_lin[c * NH + i], hf[b * 36 + i], acc);
            }
            out[((size_t)blk * BPW + b) * NC + c] = acc;
        }
    }
}

extern "C" void kernel_launch(void* const* d_in, const int* in_sizes, int n_in,
                              void* d_out, int out_size, void* d_ws, size_t ws_size,
                              hipStream_t stream) {
    const float* inp   = (const float*)d_in[0];
    const float* W_ih  = (const float*)d_in[1];
    const float* W_hh  = (const float*)d_in[2];
    const float* b_mod = (const float*)d_in[3];
    const float* W_lin = (const float*)d_in[4];
    const float* b_lin = (const float*)d_in[5];
    float* out = (float*)d_out;

    dim3 grid(NBATCH / BPW);   // 512 blocks
    dim3 block(128);           // two waves: row-groups 0 and 1
    rnn_rowsplit2<<<grid, block, 0, stream>>>(inp, W_ih, W_hh, b_mod,
                                              W_lin, b_lin, out);
}